// Round 9
// baseline (1271.025 us; speedup 1.0000x reference)
//
#include <hip/hip_runtime.h>
#include <float.h>
#include <math.h>

#define DIM    1024
#define NROWS  131072
#define TOPK   32
#define TAU    0.2f
#define CHUNK  512
#define NCHUNK (NROWS / CHUNK)   // 256
#define NCAND  (NCHUNK * TOPK)   // 8192

#define LOG_BLOCKS 2048
#define ROWS_PER_WAVE 16
#define NITER 8
#define PROBE_PASSES 6           // 6 x 512MB = 3GB per probe -> top-5 visible

typedef float floatx4 __attribute__((ext_vector_type(4)));

__device__ __forceinline__ floatx4 ld_nt(const float* p) {
    return __builtin_nontemporal_load(reinterpret_cast<const floatx4*>(p));
}

// ---------------------------------------------------------------------------
// PROBE 1: pure striped NT read, 6 rotated passes (3 GB). Minimal VGPRs.
// Rotation makes pass addresses distinct -> no GVN collapse. Its rocprof row
// gives the true cold-read ceiling for this pattern (hbm_gbps, FETCH_SIZE).
// ---------------------------------------------------------------------------
__global__ __launch_bounds__(256) void probe_pure_kernel(const float* __restrict__ Km,
                                                         float* __restrict__ dummy) {
    const int t = threadIdx.x;
    const int lane = t & 63;
    const int wave = t >> 6;
    const int gwave = blockIdx.x * 4 + wave;   // 0..8191

    float a0 = 0.f, a1 = 0.f, a2 = 0.f, a3 = 0.f;
    #pragma unroll 1
    for (int p = 0; p < PROBE_PASSES; ++p) {
        const int gw2 = (gwave + p * 1365) & 8191;
        const float* base = Km + (size_t)gw2 * DIM + lane * 4;
        floatx4 b[2][4];
        #pragma unroll
        for (int j = 0; j < 4; ++j) b[0][j] = ld_nt(base + j * 256);
        #pragma unroll
        for (int w = 0; w < 16; ++w) {
            const float* nbase = base + (size_t)8192 * DIM;
            if (w < 15) {
                #pragma unroll
                for (int j = 0; j < 4; ++j) b[(w + 1) & 1][j] = ld_nt(nbase + j * 256);
            }
            #pragma unroll
            for (int j = 0; j < 4; ++j) {
                floatx4 kv = b[w & 1][j];
                a0 += kv.x; a1 += kv.y; a2 += kv.z; a3 += kv.w;
            }
            base = nbase;
        }
    }
    if (lane == 0) dummy[gwave] = (a0 + a1) + (a2 + a3);
}

// ---------------------------------------------------------------------------
// PROBE 2: exact clone of the logits structure (q FMAs + per-row partial
// stores, same register profile as R8's phase A), 6 rotated passes.
// WRITE_SIZE on its rocprof row verifies the stores actually issue.
// ---------------------------------------------------------------------------
__global__ __launch_bounds__(256) void probe_fma_kernel(const float* __restrict__ Km,
                                                        const float* __restrict__ q,
                                                        float* __restrict__ pdump) {
    const int t = threadIdx.x;
    const int lane = t & 63;
    const int wave = t >> 6;
    const int gwave = blockIdx.x * 4 + wave;   // 0..8191

    floatx4 qv[4];
    #pragma unroll
    for (int j = 0; j < 4; ++j)
        qv[j] = *reinterpret_cast<const floatx4*>(q + j * 256 + lane * 4);

    #pragma unroll 1
    for (int p = 0; p < PROBE_PASSES; ++p) {
        const int gw2 = (gwave + p * 1365) & 8191;
        const float* base = Km + (size_t)gw2 * DIM + lane * 4;
        floatx4 b[2][4];
        #pragma unroll
        for (int j = 0; j < 4; ++j) b[0][j] = ld_nt(base + j * 256);

        float part[16];
        #pragma unroll
        for (int w = 0; w < 16; ++w) {
            const float* nbase = base + (size_t)8192 * DIM;
            if (w < 15) {
                #pragma unroll
                for (int j = 0; j < 4; ++j) b[(w + 1) & 1][j] = ld_nt(nbase + j * 256);
            }
            float a0 = 0.f, a1 = 0.f, a2 = 0.f, a3 = 0.f;
            #pragma unroll
            for (int j = 0; j < 4; ++j) {
                floatx4 kv = b[w & 1][j];
                floatx4 qq = qv[j];
                a0 = fmaf(kv.x, qq.x, a0);
                a1 = fmaf(kv.y, qq.y, a1);
                a2 = fmaf(kv.z, qq.z, a2);
                a3 = fmaf(kv.w, qq.w, a3);
            }
            part[w] = (a0 + a1) + (a2 + a3);
            base = nbase;
        }
        #pragma unroll
        for (int w = 0; w < 16; ++w)
            pdump[(size_t)(gw2 + 8192 * w) * 64 + lane] = part[w] * (float)(p + 1);
    }
}

// ---------------------------------------------------------------------------
// Kernel 1 (pipeline): logits[row] = dot(K[row], query). R5 version, 187.8us.
// ---------------------------------------------------------------------------
__global__ __launch_bounds__(256) void logits_kernel(const float* __restrict__ Km,
                                                     const float* __restrict__ q,
                                                     float* __restrict__ logits,
                                                     float* __restrict__ full_attn) {
    const int t    = threadIdx.x;
    const int lane = t & 63;
    const int wave = t >> 6;
    const int sub  = lane & 31;
    const int rsel = lane >> 5;

    floatx4 qv[8];
    #pragma unroll
    for (int p = 0; p < 8; ++p)
        qv[p] = *reinterpret_cast<const floatx4*>(q + p * 128 + sub * 4);

    const int gwave = blockIdx.x * 4 + wave;
    const int rbase = gwave * ROWS_PER_WAVE;
    const float* kptr = Km + (size_t)(rbase + rsel) * DIM + sub * 4;

    floatx4 buf[2][8];
    #pragma unroll
    for (int p = 0; p < 8; ++p)
        buf[0][p] = ld_nt(kptr + p * 128);

    #pragma unroll
    for (int r = 0; r < NITER; ++r) {
        const float* knext = kptr + 2 * DIM;
        if (r < NITER - 1) {
            #pragma unroll
            for (int p = 0; p < 8; ++p)
                buf[(r + 1) & 1][p] = ld_nt(knext + p * 128);
        }
        float a0 = 0.f, a1 = 0.f, a2 = 0.f, a3 = 0.f;
        #pragma unroll
        for (int p = 0; p < 8; ++p) {
            floatx4 kv = buf[r & 1][p];
            floatx4 qq = qv[p];
            a0 = fmaf(kv.x, qq.x, a0);
            a1 = fmaf(kv.y, qq.y, a1);
            a2 = fmaf(kv.z, qq.z, a2);
            a3 = fmaf(kv.w, qq.w, a3);
        }
        float acc = (a0 + a1) + (a2 + a3);
        #pragma unroll
        for (int off = 1; off < 32; off <<= 1) acc += __shfl_xor(acc, off, 64);
        if (sub == 0) {
            const int row = rbase + 2 * r + rsel;
            logits[row]    = acc;
            full_attn[row] = 0.f;
        }
        kptr = knext;
    }
}

// ---------------------------------------------------------------------------
// Kernel 2: per-block (1 wave) local top-32 of a 512-element chunk. UNCHANGED.
// ---------------------------------------------------------------------------
__global__ __launch_bounds__(64) void topk_local_kernel(const float* __restrict__ logits,
                                                        float* __restrict__ cand_val,
                                                        int* __restrict__ cand_idx) {
    const int lane = threadIdx.x;
    const int base = blockIdx.x * CHUNK;

    float v[8]; int gi[8];
    floatx4 a = *reinterpret_cast<const floatx4*>(logits + base + lane * 4);
    floatx4 b = *reinterpret_cast<const floatx4*>(logits + base + 256 + lane * 4);
    v[0] = a.x; v[1] = a.y; v[2] = a.z; v[3] = a.w;
    v[4] = b.x; v[5] = b.y; v[6] = b.z; v[7] = b.w;
    #pragma unroll
    for (int j = 0; j < 4; ++j) gi[j] = base + lane * 4 + j;
    #pragma unroll
    for (int j = 0; j < 4; ++j) gi[4 + j] = base + 256 + lane * 4 + j;

    for (int r = 0; r < TOPK; ++r) {
        float m = v[0]; int mi = gi[0];
        #pragma unroll
        for (int j = 1; j < 8; ++j)
            if (v[j] > m || (v[j] == m && gi[j] < mi)) { m = v[j]; mi = gi[j]; }
        #pragma unroll
        for (int off = 32; off > 0; off >>= 1) {
            float ov = __shfl_xor(m, off, 64);
            int   oi = __shfl_xor(mi, off, 64);
            if (ov > m || (ov == m && oi < mi)) { m = ov; mi = oi; }
        }
        #pragma unroll
        for (int j = 0; j < 8; ++j)
            if (gi[j] == mi) v[j] = -FLT_MAX;
        if (lane == 0) {
            cand_val[blockIdx.x * TOPK + r] = m;
            cand_idx[blockIdx.x * TOPK + r] = mi;
        }
    }
}

// ---------------------------------------------------------------------------
// Kernel 3: scale, global top-32, softmax, scatter, out = attn @ V. UNCHANGED.
// ---------------------------------------------------------------------------
__global__ __launch_bounds__(256) void final_kernel(const float* __restrict__ cand_val,
                                                    const int* __restrict__ cand_idx,
                                                    const float* __restrict__ q,
                                                    const float* __restrict__ Vm,
                                                    float* __restrict__ out,
                                                    float* __restrict__ full_attn) {
    const int t = threadIdx.x;
    const int lane = t & 63, wave = t >> 6;
    __shared__ float wred_v[4];
    __shared__ int   wred_i[4];
    __shared__ float tval[TOPK];
    __shared__ int   tidx[TOPK];
    __shared__ float attn_s[TOPK];
    __shared__ float red4[4];
    __shared__ float scale_s;

    float ss = 0.f;
    for (int i = t; i < DIM; i += 256) { float vq = q[i]; ss = fmaf(vq, vq, ss); }
    #pragma unroll
    for (int off = 32; off > 0; off >>= 1) ss += __shfl_xor(ss, off, 64);
    if (lane == 0) red4[wave] = ss;
    __syncthreads();
    if (t == 0) {
        float s = red4[0] + red4[1] + red4[2] + red4[3];
        scale_s = 1.0f / (fmaxf(sqrtf(s), 1e-12f) * TAU);
    }

    float v[32]; int gi[32];
    #pragma unroll
    for (int k = 0; k < 32; ++k) {
        int c = t + 256 * k;
        v[k]  = cand_val[c];
        gi[k] = cand_idx[c];
    }
    float m = v[0]; int mi = gi[0];
    #pragma unroll
    for (int k = 1; k < 32; ++k)
        if (v[k] > m || (v[k] == m && gi[k] < mi)) { m = v[k]; mi = gi[k]; }

    __syncthreads();

    for (int r = 0; r < TOPK; ++r) {
        float wm = m; int wmi = mi;
        #pragma unroll
        for (int off = 32; off > 0; off >>= 1) {
            float ov = __shfl_xor(wm, off, 64);
            int   oi = __shfl_xor(wmi, off, 64);
            if (ov > wm || (ov == wm && oi < wmi)) { wm = ov; wmi = oi; }
        }
        if (lane == 0) { wred_v[wave] = wm; wred_i[wave] = wmi; }
        __syncthreads();
        float gm = wred_v[0]; int gmi = wred_i[0];
        #pragma unroll
        for (int w = 1; w < 4; ++w) {
            float ov = wred_v[w]; int oi = wred_i[w];
            if (ov > gm || (ov == gm && oi < gmi)) { gm = ov; gmi = oi; }
        }
        if (t == 0) { tval[r] = gm; tidx[r] = gmi; }
        if (mi == gmi) {
            #pragma unroll
            for (int k = 0; k < 32; ++k)
                if (gi[k] == gmi) v[k] = -FLT_MAX;
            m = v[0]; mi = gi[0];
            #pragma unroll
            for (int k = 1; k < 32; ++k)
                if (v[k] > m || (v[k] == m && gi[k] < mi)) { m = v[k]; mi = gi[k]; }
        }
        __syncthreads();
    }

    const float scale = scale_s;
    float sum = 0.f;
    #pragma unroll
    for (int j = 0; j < TOPK; ++j) sum += expf((tval[j] - tval[0]) * scale);
    if (t < TOPK) attn_s[t] = expf((tval[t] - tval[0]) * scale) / sum;
    __syncthreads();

    if (t < TOPK) full_attn[tidx[t]] = attn_s[t];

    for (int d = t; d < DIM; d += 256) {
        float acc = 0.f;
        #pragma unroll
        for (int j = 0; j < TOPK; ++j)
            acc = fmaf(attn_s[j], Vm[(size_t)tidx[j] * DIM + d], acc);
        out[d] = acc;
    }
}

// ---------------------------------------------------------------------------
extern "C" void kernel_launch(void* const* d_in, const int* in_sizes, int n_in,
                              void* d_out, int out_size, void* d_ws, size_t ws_size,
                              hipStream_t stream) {
    const float* q  = (const float*)d_in[0];
    const float* Km = (const float*)d_in[1];
    const float* Vm = (const float*)d_in[2];

    float* out       = (float*)d_out;       // [0 .. 1024)
    float* full_attn = out + DIM;           // [1024 .. 1024+131072)

    float* logits   = (float*)d_ws;                 // NROWS floats
    float* cand_val = logits + NROWS;               // NCAND floats
    int*   cand_idx = (int*)(cand_val + NCAND);     // NCAND ints
    float* pdump    = (float*)(cand_idx + NCAND);   // NROWS*64 floats = 33.5 MB
    float* dummy    = pdump + (size_t)NROWS * 64;   // 8192 floats

    // pipeline (unchanged R5 structure)
    logits_kernel<<<LOG_BLOCKS, 256, 0, stream>>>(Km, q, logits, full_attn);
    topk_local_kernel<<<NCHUNK, 64, 0, stream>>>(logits, cand_val, cand_idx);
    final_kernel<<<1, 256, 0, stream>>>(cand_val, cand_idx, q, Vm, out, full_attn);
    // measurement probes (top-5-visible; removed next round)
    probe_pure_kernel<<<LOG_BLOCKS, 256, 0, stream>>>(Km, dummy);
    probe_fma_kernel<<<LOG_BLOCKS, 256, 0, stream>>>(Km, q, pdump);
}

// Round 11
// 186.691 us; speedup vs baseline: 6.8082x; 6.8082x over previous
//
#include <hip/hip_runtime.h>
#include <float.h>
#include <math.h>

#define DIM    1024
#define NROWS  131072
#define TOPK   32
#define TAU    0.2f
#define CHUNK  512
#define NCHUNK (NROWS / CHUNK)   // 256
#define NCAND  (NCHUNK * TOPK)   // 8192

#define LOG_BLOCKS 2048          // 8192 waves
#define HALF   (NROWS / 2)       // 65536 rows = 256 MB = L3 size

typedef float floatx4 __attribute__((ext_vector_type(4)));

// NT load: no L3 allocation -> the B-stream doesn't evict the pinned A-half.
__device__ __forceinline__ floatx4 ld_nt(const float* p) {
    return __builtin_nontemporal_load(reinterpret_cast<const floatx4*>(p));
}
__device__ __forceinline__ floatx4 ld(const float* p) {
    return *reinterpret_cast<const floatx4*>(p);
}

// ---------------------------------------------------------------------------
// Kernel 1: logits[row] = dot(K[row], query); zeroes full_attn[row].
//
// L3-RESIDENT / STREAMING SPLIT (R9 probe evidence: L3 serves reads
// concurrently with HBM cold reads at ~3.3 TB/s; delivered 5-7 TB/s when
// ~half the stream hits L3):
//   A half = rows [0, 65536)       : normal loads -> allocate in L3 (256 MB)
//   B half = rows [65536, 131072)  : NT loads -> stream from HBM, no evict.
// Wave g (0..8191): 8 iterations, alternating A/B pairs; 2 rows/iter (rsel),
// 32 lanes/row, register double-buffer.
//   it even: A rows g*8 + (it>>1)*2 + rsel      (covers g*8 .. g*8+7)
//   it odd : B rows HALF + g*8 + (it>>1)*2 + rsel
// Coverage: 8192 waves x 16 rows = 131072, max row index 131071. No overlap.
// ---------------------------------------------------------------------------
__global__ __launch_bounds__(256) void logits_kernel(const float* __restrict__ Km,
                                                     const float* __restrict__ q,
                                                     float* __restrict__ logits,
                                                     float* __restrict__ full_attn) {
    const int t    = threadIdx.x;
    const int lane = t & 63;
    const int wave = t >> 6;
    const int sub  = lane & 31;   // position within row
    const int rsel = lane >> 5;   // which of the pair's 2 rows

    floatx4 qv[8];
    #pragma unroll
    for (int p = 0; p < 8; ++p)
        qv[p] = *reinterpret_cast<const floatx4*>(q + p * 128 + sub * 4);

    const int g = blockIdx.x * 4 + wave;   // 0..8191

    // row for iteration 'it' in [0,8): even = A-half, odd = B-half
    #define ROW_OF(it) ((((it) & 1) ? HALF : 0) + g * 8 + ((it) >> 1) * 2 + rsel)

    floatx4 buf[2][8];
    {
        const float* p0 = Km + (size_t)ROW_OF(0) * DIM + sub * 4;
        #pragma unroll
        for (int p = 0; p < 8; ++p) buf[0][p] = ld(p0 + p * 128);
    }

    #pragma unroll
    for (int it = 0; it < 8; ++it) {
        if (it < 7) {
            const float* pn = Km + (size_t)ROW_OF(it + 1) * DIM + sub * 4;
            if ((it + 1) & 1) {   // next is B-half: NT loads
                #pragma unroll
                for (int p = 0; p < 8; ++p) buf[(it + 1) & 1][p] = ld_nt(pn + p * 128);
            } else {              // next is A-half: allocating loads
                #pragma unroll
                for (int p = 0; p < 8; ++p) buf[(it + 1) & 1][p] = ld(pn + p * 128);
            }
        }
        float a0 = 0.f, a1 = 0.f, a2 = 0.f, a3 = 0.f;
        #pragma unroll
        for (int p = 0; p < 8; ++p) {
            floatx4 kv = buf[it & 1][p];
            floatx4 qq = qv[p];
            a0 = fmaf(kv.x, qq.x, a0);
            a1 = fmaf(kv.y, qq.y, a1);
            a2 = fmaf(kv.z, qq.z, a2);
            a3 = fmaf(kv.w, qq.w, a3);
        }
        float acc = (a0 + a1) + (a2 + a3);
        #pragma unroll
        for (int off = 1; off < 32; off <<= 1) acc += __shfl_xor(acc, off, 64);
        if (sub == 0) {
            const int row = ROW_OF(it);
            logits[row]    = acc;
            full_attn[row] = 0.f;
        }
    }
    #undef ROW_OF
}

// ---------------------------------------------------------------------------
// Kernel 2: per-block (1 wave) local top-32 of a 512-element chunk. UNCHANGED.
// ---------------------------------------------------------------------------
__global__ __launch_bounds__(64) void topk_local_kernel(const float* __restrict__ logits,
                                                        float* __restrict__ cand_val,
                                                        int* __restrict__ cand_idx) {
    const int lane = threadIdx.x;
    const int base = blockIdx.x * CHUNK;

    float v[8]; int gi[8];
    floatx4 a = *reinterpret_cast<const floatx4*>(logits + base + lane * 4);
    floatx4 b = *reinterpret_cast<const floatx4*>(logits + base + 256 + lane * 4);
    v[0] = a.x; v[1] = a.y; v[2] = a.z; v[3] = a.w;
    v[4] = b.x; v[5] = b.y; v[6] = b.z; v[7] = b.w;
    #pragma unroll
    for (int j = 0; j < 4; ++j) gi[j] = base + lane * 4 + j;
    #pragma unroll
    for (int j = 0; j < 4; ++j) gi[4 + j] = base + 256 + lane * 4 + j;

    for (int r = 0; r < TOPK; ++r) {
        float m = v[0]; int mi = gi[0];
        #pragma unroll
        for (int j = 1; j < 8; ++j)
            if (v[j] > m || (v[j] == m && gi[j] < mi)) { m = v[j]; mi = gi[j]; }
        #pragma unroll
        for (int off = 32; off > 0; off >>= 1) {
            float ov = __shfl_xor(m, off, 64);
            int   oi = __shfl_xor(mi, off, 64);
            if (ov > m || (ov == m && oi < mi)) { m = ov; mi = oi; }
        }
        #pragma unroll
        for (int j = 0; j < 8; ++j)
            if (gi[j] == mi) v[j] = -FLT_MAX;
        if (lane == 0) {
            cand_val[blockIdx.x * TOPK + r] = m;
            cand_idx[blockIdx.x * TOPK + r] = mi;
        }
    }
}

// ---------------------------------------------------------------------------
// Kernel 3: scale, global top-32, softmax, scatter, out = attn @ V. UNCHANGED.
// ---------------------------------------------------------------------------
__global__ __launch_bounds__(256) void final_kernel(const float* __restrict__ cand_val,
                                                    const int* __restrict__ cand_idx,
                                                    const float* __restrict__ q,
                                                    const float* __restrict__ Vm,
                                                    float* __restrict__ out,
                                                    float* __restrict__ full_attn) {
    const int t = threadIdx.x;
    const int lane = t & 63, wave = t >> 6;
    __shared__ float wred_v[4];
    __shared__ int   wred_i[4];
    __shared__ float tval[TOPK];
    __shared__ int   tidx[TOPK];
    __shared__ float attn_s[TOPK];
    __shared__ float red4[4];
    __shared__ float scale_s;

    float ss = 0.f;
    for (int i = t; i < DIM; i += 256) { float vq = q[i]; ss = fmaf(vq, vq, ss); }
    #pragma unroll
    for (int off = 32; off > 0; off >>= 1) ss += __shfl_xor(ss, off, 64);
    if (lane == 0) red4[wave] = ss;
    __syncthreads();
    if (t == 0) {
        float s = red4[0] + red4[1] + red4[2] + red4[3];
        scale_s = 1.0f / (fmaxf(sqrtf(s), 1e-12f) * TAU);
    }

    float v[32]; int gi[32];
    #pragma unroll
    for (int k = 0; k < 32; ++k) {
        int c = t + 256 * k;
        v[k]  = cand_val[c];
        gi[k] = cand_idx[c];
    }
    float m = v[0]; int mi = gi[0];
    #pragma unroll
    for (int k = 1; k < 32; ++k)
        if (v[k] > m || (v[k] == m && gi[k] < mi)) { m = v[k]; mi = gi[k]; }

    __syncthreads();

    for (int r = 0; r < TOPK; ++r) {
        float wm = m; int wmi = mi;
        #pragma unroll
        for (int off = 32; off > 0; off >>= 1) {
            float ov = __shfl_xor(wm, off, 64);
            int   oi = __shfl_xor(wmi, off, 64);
            if (ov > wm || (ov == wm && oi < wmi)) { wm = ov; wmi = oi; }
        }
        if (lane == 0) { wred_v[wave] = wm; wred_i[wave] = wmi; }
        __syncthreads();
        float gm = wred_v[0]; int gmi = wred_i[0];
        #pragma unroll
        for (int w = 1; w < 4; ++w) {
            float ov = wred_v[w]; int oi = wred_i[w];
            if (ov > gm || (ov == gm && oi < gmi)) { gm = ov; gmi = oi; }
        }
        if (t == 0) { tval[r] = gm; tidx[r] = gmi; }
        if (mi == gmi) {
            #pragma unroll
            for (int k = 0; k < 32; ++k)
                if (gi[k] == gmi) v[k] = -FLT_MAX;
            m = v[0]; mi = gi[0];
            #pragma unroll
            for (int k = 1; k < 32; ++k)
                if (v[k] > m || (v[k] == m && gi[k] < mi)) { m = v[k]; mi = gi[k]; }
        }
        __syncthreads();
    }

    const float scale = scale_s;
    float sum = 0.f;
    #pragma unroll
    for (int j = 0; j < TOPK; ++j) sum += expf((tval[j] - tval[0]) * scale);
    if (t < TOPK) attn_s[t] = expf((tval[t] - tval[0]) * scale) / sum;
    __syncthreads();

    if (t < TOPK) full_attn[tidx[t]] = attn_s[t];

    for (int d = t; d < DIM; d += 256) {
        float acc = 0.f;
        #pragma unroll
        for (int j = 0; j < TOPK; ++j)
            acc = fmaf(attn_s[j], Vm[(size_t)tidx[j] * DIM + d], acc);
        out[d] = acc;
    }
}

// ---------------------------------------------------------------------------
extern "C" void kernel_launch(void* const* d_in, const int* in_sizes, int n_in,
                              void* d_out, int out_size, void* d_ws, size_t ws_size,
                              hipStream_t stream) {
    const float* q  = (const float*)d_in[0];
    const float* Km = (const float*)d_in[1];
    const float* Vm = (const float*)d_in[2];

    float* out       = (float*)d_out;       // [0 .. 1024)
    float* full_attn = out + DIM;           // [1024 .. 1024+131072)

    float* logits   = (float*)d_ws;                 // NROWS floats
    float* cand_val = logits + NROWS;               // NCAND floats
    int*   cand_idx = (int*)(cand_val + NCAND);     // NCAND ints

    logits_kernel<<<LOG_BLOCKS, 256, 0, stream>>>(Km, q, logits, full_attn);
    topk_local_kernel<<<NCHUNK, 64, 0, stream>>>(logits, cand_val, cand_idx);
    final_kernel<<<1, 256, 0, stream>>>(cand_val, cand_idx, q, Vm, out, full_attn);
}

// Round 12
// 185.094 us; speedup vs baseline: 6.8669x; 1.0086x over previous
//
#include <hip/hip_runtime.h>
#include <float.h>
#include <math.h>

#define DIM    1024
#define NROWS  131072
#define TOPK   32
#define TAU    0.2f
#define CHUNK  512
#define NCHUNK (NROWS / CHUNK)   // 256
#define NCAND  (NCHUNK * TOPK)   // 8192

typedef float floatx4 __attribute__((ext_vector_type(4)));

__device__ __forceinline__ floatx4 ld_nt(const float* p) {
    return __builtin_nontemporal_load(reinterpret_cast<const floatx4*>(p));
}

// ---------------------------------------------------------------------------
// FUSED kernel 1: block b computes logits for chunk rows [b*512, b*512+512)
// (NT double-buffered K stream at the ~3.3 TB/s read ceiling), stores them in
// LDS, zeroes full_attn for those rows, then wave 0 extracts the chunk-local
// top-32 -> candidate arrays. Eliminates the global logits array + 1 launch.
// 8 waves/block; wave w owns rows b*512 + w*64 + [0..63] (2 rows/iter, 32
// lanes/row, register double-buffer; same inner loop as the R5/R11 kernel).
// ---------------------------------------------------------------------------
__global__ __launch_bounds__(512) void logits_topk_kernel(const float* __restrict__ Km,
                                                          const float* __restrict__ q,
                                                          float* __restrict__ cand_val,
                                                          int* __restrict__ cand_idx,
                                                          float* __restrict__ full_attn) {
    __shared__ float loc[CHUNK];

    const int t    = threadIdx.x;
    const int lane = t & 63;
    const int wave = t >> 6;      // 0..7
    const int sub  = lane & 31;   // position within row
    const int rsel = lane >> 5;   // which of the pair's 2 rows

    floatx4 qv[8];
    #pragma unroll
    for (int p = 0; p < 8; ++p)
        qv[p] = *reinterpret_cast<const floatx4*>(q + p * 128 + sub * 4);

    const int chunk_base = blockIdx.x * CHUNK;
    const int rbase = chunk_base + wave * 64;          // this wave's 64 rows
    const float* kptr = Km + (size_t)(rbase + rsel) * DIM + sub * 4;

    floatx4 buf[2][8];
    #pragma unroll
    for (int p = 0; p < 8; ++p)
        buf[0][p] = ld_nt(kptr + p * 128);

    #pragma unroll
    for (int r = 0; r < 32; ++r) {                     // 32 pair-iters = 64 rows
        const float* knext = kptr + 2 * DIM;
        if (r < 31) {
            #pragma unroll
            for (int p = 0; p < 8; ++p)
                buf[(r + 1) & 1][p] = ld_nt(knext + p * 128);
        }
        float a0 = 0.f, a1 = 0.f, a2 = 0.f, a3 = 0.f;
        #pragma unroll
        for (int p = 0; p < 8; ++p) {
            floatx4 kv = buf[r & 1][p];
            floatx4 qq = qv[p];
            a0 = fmaf(kv.x, qq.x, a0);
            a1 = fmaf(kv.y, qq.y, a1);
            a2 = fmaf(kv.z, qq.z, a2);
            a3 = fmaf(kv.w, qq.w, a3);
        }
        float acc = (a0 + a1) + (a2 + a3);
        #pragma unroll
        for (int off = 1; off < 32; off <<= 1) acc += __shfl_xor(acc, off, 64);
        if (sub == 0) {
            const int row = rbase + 2 * r + rsel;
            loc[row - chunk_base] = acc;
            full_attn[row] = 0.f;
        }
        kptr = knext;
    }

    __syncthreads();

    // ---- wave 0: chunk-local top-32 of loc[0..511] (val desc, idx asc) ----
    if (wave == 0) {
        float v[8]; int gi[8];
        #pragma unroll
        for (int j = 0; j < 8; ++j) {
            v[j]  = loc[lane * 8 + j];
            gi[j] = chunk_base + lane * 8 + j;
        }
        for (int r = 0; r < TOPK; ++r) {
            float m = v[0]; int mi = gi[0];
            #pragma unroll
            for (int j = 1; j < 8; ++j)
                if (v[j] > m || (v[j] == m && gi[j] < mi)) { m = v[j]; mi = gi[j]; }
            #pragma unroll
            for (int off = 32; off > 0; off >>= 1) {
                float ov = __shfl_xor(m, off, 64);
                int   oi = __shfl_xor(mi, off, 64);
                if (ov > m || (ov == m && oi < mi)) { m = ov; mi = oi; }
            }
            #pragma unroll
            for (int j = 0; j < 8; ++j)
                if (gi[j] == mi) v[j] = -FLT_MAX;   // unique owner
            if (lane == 0) {
                cand_val[blockIdx.x * TOPK + r] = m;
                cand_idx[blockIdx.x * TOPK + r] = mi;
            }
        }
    }
}

// ---------------------------------------------------------------------------
// Kernel 2 (1 block, 256 threads): scale = 1/(max(||q||,1e-12)*TAU), global
// top-32 of 8192 candidates, softmax, scatter into full_attn, out = attn@V.
// UNCHANGED from R11.
// ---------------------------------------------------------------------------
__global__ __launch_bounds__(256) void final_kernel(const float* __restrict__ cand_val,
                                                    const int* __restrict__ cand_idx,
                                                    const float* __restrict__ q,
                                                    const float* __restrict__ Vm,
                                                    float* __restrict__ out,
                                                    float* __restrict__ full_attn) {
    const int t = threadIdx.x;
    const int lane = t & 63, wave = t >> 6;
    __shared__ float wred_v[4];
    __shared__ int   wred_i[4];
    __shared__ float tval[TOPK];
    __shared__ int   tidx[TOPK];
    __shared__ float attn_s[TOPK];
    __shared__ float red4[4];
    __shared__ float scale_s;

    float ss = 0.f;
    for (int i = t; i < DIM; i += 256) { float vq = q[i]; ss = fmaf(vq, vq, ss); }
    #pragma unroll
    for (int off = 32; off > 0; off >>= 1) ss += __shfl_xor(ss, off, 64);
    if (lane == 0) red4[wave] = ss;
    __syncthreads();
    if (t == 0) {
        float s = red4[0] + red4[1] + red4[2] + red4[3];
        scale_s = 1.0f / (fmaxf(sqrtf(s), 1e-12f) * TAU);
    }

    float v[32]; int gi[32];
    #pragma unroll
    for (int k = 0; k < 32; ++k) {
        int c = t + 256 * k;
        v[k]  = cand_val[c];
        gi[k] = cand_idx[c];
    }
    float m = v[0]; int mi = gi[0];
    #pragma unroll
    for (int k = 1; k < 32; ++k)
        if (v[k] > m || (v[k] == m && gi[k] < mi)) { m = v[k]; mi = gi[k]; }

    __syncthreads();

    for (int r = 0; r < TOPK; ++r) {
        float wm = m; int wmi = mi;
        #pragma unroll
        for (int off = 32; off > 0; off >>= 1) {
            float ov = __shfl_xor(wm, off, 64);
            int   oi = __shfl_xor(wmi, off, 64);
            if (ov > wm || (ov == wm && oi < wmi)) { wm = ov; wmi = oi; }
        }
        if (lane == 0) { wred_v[wave] = wm; wred_i[wave] = wmi; }
        __syncthreads();
        float gm = wred_v[0]; int gmi = wred_i[0];
        #pragma unroll
        for (int w = 1; w < 4; ++w) {
            float ov = wred_v[w]; int oi = wred_i[w];
            if (ov > gm || (ov == gm && oi < gmi)) { gm = ov; gmi = oi; }
        }
        if (t == 0) { tval[r] = gm; tidx[r] = gmi; }
        if (mi == gmi) {
            #pragma unroll
            for (int k = 0; k < 32; ++k)
                if (gi[k] == gmi) v[k] = -FLT_MAX;
            m = v[0]; mi = gi[0];
            #pragma unroll
            for (int k = 1; k < 32; ++k)
                if (v[k] > m || (v[k] == m && gi[k] < mi)) { m = v[k]; mi = gi[k]; }
        }
        __syncthreads();
    }

    const float scale = scale_s;
    float sum = 0.f;
    #pragma unroll
    for (int j = 0; j < TOPK; ++j) sum += expf((tval[j] - tval[0]) * scale);
    if (t < TOPK) attn_s[t] = expf((tval[t] - tval[0]) * scale) / sum;
    __syncthreads();

    if (t < TOPK) full_attn[tidx[t]] = attn_s[t];

    for (int d = t; d < DIM; d += 256) {
        float acc = 0.f;
        #pragma unroll
        for (int j = 0; j < TOPK; ++j)
            acc = fmaf(attn_s[j], Vm[(size_t)tidx[j] * DIM + d], acc);
        out[d] = acc;
    }
}

// ---------------------------------------------------------------------------
extern "C" void kernel_launch(void* const* d_in, const int* in_sizes, int n_in,
                              void* d_out, int out_size, void* d_ws, size_t ws_size,
                              hipStream_t stream) {
    const float* q  = (const float*)d_in[0];
    const float* Km = (const float*)d_in[1];
    const float* Vm = (const float*)d_in[2];

    float* out       = (float*)d_out;       // [0 .. 1024)
    float* full_attn = out + DIM;           // [1024 .. 1024+131072)

    float* cand_val = (float*)d_ws;                 // NCAND floats
    int*   cand_idx = (int*)(cand_val + NCAND);     // NCAND ints

    logits_topk_kernel<<<NCHUNK, 512, 0, stream>>>(Km, q, cand_val, cand_idx, full_attn);
    final_kernel<<<1, 256, 0, stream>>>(cand_val, cand_idx, q, Vm, out, full_attn);
}